// Round 6
// baseline (110.327 us; speedup 1.0000x reference)
//
#include <hip/hip_runtime.h>

typedef unsigned short u16;
typedef unsigned int u32;
typedef __attribute__((ext_vector_type(8))) short short8;
typedef __attribute__((ext_vector_type(4))) float f32x4;

__device__ __forceinline__ u16 f2b(float f) {
  u32 u = __builtin_bit_cast(u32, f);
  u32 r = (u + 0x7FFFu + ((u >> 16) & 1u)) >> 16;  // RNE f32->bf16
  return (u16)r;
}

__device__ __forceinline__ void gl_lds16(const void* g, void* l) {
  __builtin_amdgcn_global_load_lds(
      (const __attribute__((address_space(1))) u32*)g,
      (__attribute__((address_space(3))) u32*)l, 16, 0, 0);
}

struct Ptrs8 { const float* p[8]; };

// ---------------------------------------------------------------------------
// Pack/transpose+convert: Wt[g*1024 + n][h*1024 + k] = bf16(W[h*4+g][k][n])
// ---------------------------------------------------------------------------
__global__ __launch_bounds__(256) void wt_pack(Ptrs8 w, u16* __restrict__ Wt) {
  __shared__ float lds[64 * 64];     // 16 KB
  const int tid = threadIdx.x;
  const int bid = blockIdx.x;
  const int mat = bid >> 8;            // 0..7
  const int g = mat & 3, h = mat >> 2;
  const int tile = bid & 255;
  const int kt = tile >> 4, nt = tile & 15;
  const float* __restrict__ src = w.p[mat];

#pragma unroll
  for (int i = 0; i < 4; ++i) {
    int c = tid + i * 256;
    int k = c >> 4, n4 = (c & 15) * 4;
    gl_lds16(src + (size_t)(kt * 64 + k) * 1024 + nt * 64 + n4, &lds[c * 4]);
  }
  asm volatile("s_waitcnt vmcnt(0)");
  __syncthreads();

#pragma unroll
  for (int i = 0; i < 2; ++i) {
    int c = tid + i * 256;
    int n = c & 63, kb = (c >> 6) * 8;
    short8 v;
#pragma unroll
    for (int j = 0; j < 8; ++j) v[j] = (short)f2b(lds[(kb + j) * 64 + n]);
    size_t off = (size_t)(g * 1024 + nt * 64 + n) * 2048 + h * 1024 + kt * 64 + kb;
    *reinterpret_cast<short8*>(Wt + off) = v;
  }
}

// Ap[m][k] (bf16, [4096][2048]) = bf16( k<1024 ? x[m][k] : h0[m][k-1024] )
__global__ __launch_bounds__(256) void xh_pack(const float* __restrict__ x,
                                               const float* __restrict__ h0,
                                               u16* __restrict__ Ap) {
  int t = blockIdx.x * 256 + threadIdx.x;
  int m = t >> 8, kc = t & 255;
  const float* src = (kc < 128) ? (x + (size_t)m * 1024 + kc * 8)
                                : (h0 + (size_t)m * 1024 + (kc - 128) * 8);
  float4 a = *reinterpret_cast<const float4*>(src);
  float4 b = *reinterpret_cast<const float4*>(src + 4);
  short8 v;
  v[0] = (short)f2b(a.x); v[1] = (short)f2b(a.y);
  v[2] = (short)f2b(a.z); v[3] = (short)f2b(a.w);
  v[4] = (short)f2b(b.x); v[5] = (short)f2b(b.y);
  v[6] = (short)f2b(b.z); v[7] = (short)f2b(b.w);
  *reinterpret_cast<short8*>(Ap + (size_t)m * 2048 + kc * 8) = v;
}

__global__ void bias_pack(Ptrs8 b, float* __restrict__ bias) {
  int i = blockIdx.x * 1024 + threadIdx.x;
  int g = i >> 10, n = i & 1023;
  bias[i] = b.p[g][n] + b.p[4 + g][n];
}

// ---------------------------------------------------------------------------
// Fused LSTM GEMM, 8-phase-template port (free-scheduling variant):
// 512 thr / 8 waves (2M x 4N), block 256m x (64n x 4 gates), BK=64, 32 iters.
// One clobbered vmcnt(0)+barrier per iter (correctness anchor); intra-iter
// phases use bare lgkmcnt(0) + s_barrier rhythm so the compiler can hoist
// next-phase ds_reads over the current MFMA cluster (software pipelining).
// ---------------------------------------------------------------------------
#define LD8(base, off) (*reinterpret_cast<const short8*>((base) + (off)))

__global__ __launch_bounds__(512, 2) void lstm_fused(
    const u16* __restrict__ Ap, const float* __restrict__ c0,
    const u16* __restrict__ Wt, const float* __restrict__ bias,
    float* __restrict__ out) {
  __shared__ u16 As[2][256 * 64];   // 32 KB each
  __shared__ u16 Bs[2][256 * 64];   // 32 KB each

  const int tid = threadIdx.x;
  const int lane = tid & 63;
  const int wid = tid >> 6;
  const int wr = wid >> 2;          // M half
  const int wc = wid & 3;           // n-16 block
  const int fl = lane & 15;
  const int hi = lane >> 4;
  const int lo7 = fl & 7;

  const int bid0 = blockIdx.x;
  const int sbid = (bid0 & 7) * 32 + (bid0 >> 3);  // XCD swizzle (256%8==0)
  const int m0 = (sbid >> 4) * 256;
  const int n0 = (sbid & 15) * 64;

  // ---- stage maps: 2048 16B-chunks per tile, 4/thread, linear LDS dest,
  //      global source pre-swizzled: chunk cg = cL ^ (row & 7) ----
  int aoff[4], boff[4];
#pragma unroll
  for (int i = 0; i < 4; ++i) {
    const int L = tid + i * 512;
    const int r = L >> 3, cL = L & 7;
    const int cg = cL ^ (r & 7);
    aoff[i] = (m0 + r) * 2048 + cg * 8;
    const int wce = r >> 6, ge = (r >> 4) & 3, ue = r & 15;
    boff[i] = (ge * 1024 + n0 + wce * 16 + ue) * 2048 + cg * 8;
  }

  auto stageA = [&](int buf, int t) {
    const int k0 = t * 64;
#pragma unroll
    for (int i = 0; i < 4; ++i)
      gl_lds16(Ap + aoff[i] + k0, &As[buf][(tid + i * 512) * 8]);
  };
  auto stageB = [&](int buf, int t) {
    const int k0 = t * 64;
#pragma unroll
    for (int i = 0; i < 4; ++i)
      gl_lds16(Wt + boff[i] + k0, &Bs[buf][(tid + i * 512) * 8]);
  };

  // ---- fragment read bases (element offsets; lane-constant swizzle) ----
  const int c0k = (hi ^ lo7) * 8;          // ks=0 swizzled chunk
  const int c1k = ((4 + hi) ^ lo7) * 8;    // ks=1
  const int arow = (wr * 128 + fl) * 64;
  const int brow = (wc * 64 + fl) * 64;

  f32x4 acc[8][4] = {};   // [mi][gate]

  stageA(0, 0);
  stageB(0, 0);

#define PH_A_MFMA(MI0)                                                        \
  do {                                                                        \
    short8 a00 = LD8(Ab, arow + (MI0) * 1024 + c0k);                          \
    short8 a01 = LD8(Ab, arow + (MI0) * 1024 + c1k);                          \
    short8 a10 = LD8(Ab, arow + (MI0 + 1) * 1024 + c0k);                      \
    short8 a11 = LD8(Ab, arow + (MI0 + 1) * 1024 + c1k);                      \
    __builtin_amdgcn_s_barrier();                                             \
    asm volatile("s_waitcnt lgkmcnt(0)");                                     \
    __builtin_amdgcn_s_setprio(1);                                            \
    _Pragma("unroll")                                                         \
    for (int g = 0; g < 4; ++g) {                                             \
      acc[MI0][g] = __builtin_amdgcn_mfma_f32_16x16x32_bf16(                  \
          a00, bf[g][0], acc[MI0][g], 0, 0, 0);                               \
      acc[MI0][g] = __builtin_amdgcn_mfma_f32_16x16x32_bf16(                  \
          a01, bf[g][1], acc[MI0][g], 0, 0, 0);                               \
      acc[MI0 + 1][g] = __builtin_amdgcn_mfma_f32_16x16x32_bf16(              \
          a10, bf[g][0], acc[MI0 + 1][g], 0, 0, 0);                           \
      acc[MI0 + 1][g] = __builtin_amdgcn_mfma_f32_16x16x32_bf16(              \
          a11, bf[g][1], acc[MI0 + 1][g], 0, 0, 0);                           \
    }                                                                         \
    __builtin_amdgcn_s_setprio(0);                                            \
    __builtin_amdgcn_s_barrier();                                             \
  } while (0)

  for (int t = 0; t < 32; ++t) {
    const int cur = t & 1;
    const u16* Ab = &As[cur][0];
    const u16* Bb = &Bs[cur][0];

    // iter top: tile t's 8 loads landed (issued a full iter ago -> no stall).
    // The memory clobber is the single ordering anchor per iter.
    asm volatile("s_waitcnt vmcnt(0)" ::: "memory");
    __builtin_amdgcn_s_barrier();
    if (t < 31) {
      stageA(cur ^ 1, t + 1);
      stageB(cur ^ 1, t + 1);
    }

    // B fragments (live across the iter), then 4 MFMA phases
    short8 bf[4][2];
#pragma unroll
    for (int g = 0; g < 4; ++g) {
      bf[g][0] = LD8(Bb, brow + g * 1024 + c0k);
      bf[g][1] = LD8(Bb, brow + g * 1024 + c1k);
    }
    PH_A_MFMA(0);
    PH_A_MFMA(2);
    PH_A_MFMA(4);
    PH_A_MFMA(6);
  }

  // ---- fused epilogue: bias + gates + cell update ----
  const int col = n0 + wc * 16 + fl;
  float bv[4];
#pragma unroll
  for (int g = 0; g < 4; ++g) bv[g] = bias[g * 1024 + col];

#pragma unroll
  for (int mi = 0; mi < 8; ++mi) {
#pragma unroll
    for (int r = 0; r < 4; ++r) {
      const int row = m0 + wr * 128 + mi * 16 + hi * 4 + r;
      const float zi = acc[mi][0][r] + bv[0];
      const float zf = acc[mi][1][r] + bv[1];
      const float zg = acc[mi][2][r] + bv[2];
      const float zo = acc[mi][3][r] + bv[3];
      const float ig = 1.f / (1.f + __expf(-zi));
      const float fg = 1.f / (1.f + __expf(-zf));
      const float gg = 1.f - 2.f / (__expf(2.f * zg) + 1.f);  // tanh
      const float og = 1.f / (1.f + __expf(-zo));
      const float c0v = c0[(size_t)row * 1024 + col];
      const float c1 = fg * c0v + ig * gg;
      const float h1 = og * c1;
      out[(size_t)row * 1024 + col] = h1;
      out[(size_t)4194304 + (size_t)row * 1024 + col] = c1;
    }
  }
}

// ---------------------------------------------------------------------------
extern "C" void kernel_launch(void* const* d_in, const int* in_sizes, int n_in,
                              void* d_out, int out_size, void* d_ws, size_t ws_size,
                              hipStream_t stream) {
  const float* x  = (const float*)d_in[0];
  const float* h0 = (const float*)d_in[1];
  const float* c0 = (const float*)d_in[2];
  Ptrs8 w, b;
  for (int i = 0; i < 4; ++i) {
    w.p[i]     = (const float*)d_in[3 + 2 * i];
    b.p[i]     = (const float*)d_in[4 + 2 * i];
    w.p[4 + i] = (const float*)d_in[11 + 2 * i];
    b.p[4 + i] = (const float*)d_in[12 + 2 * i];
  }
  u16* Wt = (u16*)d_ws;                                        // 16 MB
  u16* Ap = (u16*)((char*)d_ws + (size_t)4096 * 2048 * 2);     // 16 MB
  float* bias = (float*)((char*)d_ws + (size_t)2 * 4096 * 2048 * 2);  // 16 KB
  float* out = (float*)d_out;

  wt_pack<<<2048, 256, 0, stream>>>(w, Wt);
  xh_pack<<<4096, 256, 0, stream>>>(x, h0, Ap);
  bias_pack<<<4, 1024, 0, stream>>>(b, bias);
  lstm_fused<<<256, 512, 0, stream>>>(Ap, c0, Wt, bias, out);
}

// Round 7
// 93.627 us; speedup vs baseline: 1.1784x; 1.1784x over previous
//
#include <hip/hip_runtime.h>

typedef unsigned short u16;
typedef unsigned int u32;
typedef __attribute__((ext_vector_type(8))) short short8;
typedef __attribute__((ext_vector_type(4))) float f32x4;

__device__ __forceinline__ u16 f2b(float f) {
  u32 u = __builtin_bit_cast(u32, f);
  u32 r = (u + 0x7FFFu + ((u >> 16) & 1u)) >> 16;  // RNE f32->bf16
  return (u16)r;
}

__device__ __forceinline__ void gl_lds16(const void* g, void* l) {
  __builtin_amdgcn_global_load_lds(
      (const __attribute__((address_space(1))) u32*)g,
      (__attribute__((address_space(3))) u32*)l, 16, 0, 0);
}

struct Ptrs8 { const float* p[8]; };

// ---------------------------------------------------------------------------
// Pack/transpose+convert: Wt[g*1024 + n][h*1024 + k] = bf16(W[h*4+g][k][n])
// ---------------------------------------------------------------------------
__global__ __launch_bounds__(256) void wt_pack(Ptrs8 w, u16* __restrict__ Wt) {
  __shared__ float lds[64 * 64];     // 16 KB
  const int tid = threadIdx.x;
  const int bid = blockIdx.x;
  const int mat = bid >> 8;            // 0..7
  const int g = mat & 3, h = mat >> 2;
  const int tile = bid & 255;
  const int kt = tile >> 4, nt = tile & 15;
  const float* __restrict__ src = w.p[mat];

#pragma unroll
  for (int i = 0; i < 4; ++i) {
    int c = tid + i * 256;
    int k = c >> 4, n4 = (c & 15) * 4;
    gl_lds16(src + (size_t)(kt * 64 + k) * 1024 + nt * 64 + n4, &lds[c * 4]);
  }
  asm volatile("s_waitcnt vmcnt(0)");
  __syncthreads();

#pragma unroll
  for (int i = 0; i < 2; ++i) {
    int c = tid + i * 256;
    int n = c & 63, kb = (c >> 6) * 8;
    short8 v;
#pragma unroll
    for (int j = 0; j < 8; ++j) v[j] = (short)f2b(lds[(kb + j) * 64 + n]);
    size_t off = (size_t)(g * 1024 + nt * 64 + n) * 2048 + h * 1024 + kt * 64 + kb;
    *reinterpret_cast<short8*>(Wt + off) = v;
  }
}

// Ap[m][k] (bf16, [4096][2048]) = bf16( k<1024 ? x[m][k] : h0[m][k-1024] )
__global__ __launch_bounds__(256) void xh_pack(const float* __restrict__ x,
                                               const float* __restrict__ h0,
                                               u16* __restrict__ Ap) {
  int t = blockIdx.x * 256 + threadIdx.x;
  int m = t >> 8, kc = t & 255;
  const float* src = (kc < 128) ? (x + (size_t)m * 1024 + kc * 8)
                                : (h0 + (size_t)m * 1024 + (kc - 128) * 8);
  float4 a = *reinterpret_cast<const float4*>(src);
  float4 b = *reinterpret_cast<const float4*>(src + 4);
  short8 v;
  v[0] = (short)f2b(a.x); v[1] = (short)f2b(a.y);
  v[2] = (short)f2b(a.z); v[3] = (short)f2b(a.w);
  v[4] = (short)f2b(b.x); v[5] = (short)f2b(b.y);
  v[6] = (short)f2b(b.z); v[7] = (short)f2b(b.w);
  *reinterpret_cast<short8*>(Ap + (size_t)m * 2048 + kc * 8) = v;
}

__global__ void bias_pack(Ptrs8 b, float* __restrict__ bias) {
  int i = blockIdx.x * 1024 + threadIdx.x;
  int g = i >> 10, n = i & 1023;
  bias[i] = b.p[g][n] + b.p[4 + g][n];
}

// ---------------------------------------------------------------------------
// Fused LSTM GEMM — big-cluster schedule:
// 512 thr / 8 waves (2M x 4N), block 256m x (64n x 4 gates), BK=64, 32 iters.
// Per iter: [vmcnt(8) bar] [24 ds_read_b128 -> regs] [lgkm(0) bar]
//           [stage tile t+2 into just-freed buffer] [64 reg-only MFMA].
// 2 barriers/iter (was 9); 2-tile prefetch depth with 2 buffers (early free);
// staging DMA overlaps the MFMA cluster. 3-bit XOR chunk swizzle as before.
// ---------------------------------------------------------------------------
#define LD8(base, off) (*reinterpret_cast<const short8*>((base) + (off)))

__global__ __launch_bounds__(512, 2) void lstm_fused(
    const u16* __restrict__ Ap, const float* __restrict__ c0,
    const u16* __restrict__ Wt, const float* __restrict__ bias,
    float* __restrict__ out) {
  __shared__ u16 As[2][256 * 64];   // 32 KB each
  __shared__ u16 Bs[2][256 * 64];   // 32 KB each

  const int tid = threadIdx.x;
  const int lane = tid & 63;
  const int wid = tid >> 6;
  const int wr = wid >> 2;          // M half
  const int wc = wid & 3;           // n-16 block
  const int fl = lane & 15;
  const int hi = lane >> 4;
  const int lo7 = fl & 7;

  const int bid0 = blockIdx.x;
  const int sbid = (bid0 & 7) * 32 + (bid0 >> 3);  // XCD swizzle (256%8==0)
  const int m0 = (sbid >> 4) * 256;
  const int n0 = (sbid & 15) * 64;

  // ---- stage maps: 2048 16B-chunks per tile, 4/thread, linear LDS dest,
  //      global source pre-swizzled: chunk cg = cL ^ (row & 7) ----
  int aoff[4], boff[4];
#pragma unroll
  for (int i = 0; i < 4; ++i) {
    const int L = tid + i * 512;
    const int r = L >> 3, cL = L & 7;
    const int cg = cL ^ (r & 7);
    aoff[i] = (m0 + r) * 2048 + cg * 8;
    const int wce = r >> 6, ge = (r >> 4) & 3, ue = r & 15;
    boff[i] = (ge * 1024 + n0 + wce * 16 + ue) * 2048 + cg * 8;
  }

  auto stageA = [&](int buf, int t) {
    const int k0 = t * 64;
#pragma unroll
    for (int i = 0; i < 4; ++i)
      gl_lds16(Ap + aoff[i] + k0, &As[buf][(tid + i * 512) * 8]);
  };
  auto stageB = [&](int buf, int t) {
    const int k0 = t * 64;
#pragma unroll
    for (int i = 0; i < 4; ++i)
      gl_lds16(Wt + boff[i] + k0, &Bs[buf][(tid + i * 512) * 8]);
  };

  // ---- fragment read bases (element offsets; lane-constant swizzle) ----
  const int c0k = (hi ^ lo7) * 8;          // ks=0 swizzled chunk
  const int c1k = ((4 + hi) ^ lo7) * 8;    // ks=1
  const int arow = (wr * 128 + fl) * 64;
  const int brow = (wc * 64 + fl) * 64;

  f32x4 acc[8][4] = {};   // [mi][gate]

  // prologue: 2 tiles in flight (16 loads/thread)
  stageA(0, 0);
  stageB(0, 0);
  stageA(1, 1);
  stageB(1, 1);

  for (int t = 0; t < 32; ++t) {
    const int cur = t & 1;
    const u16* Ab = &As[cur][0];
    const u16* Bb = &Bs[cur][0];

    // tile t landed (stage(t+1)'s 8 loads stay in flight)
    if (t < 31) {
      asm volatile("s_waitcnt vmcnt(8)" ::: "memory");
    } else {
      asm volatile("s_waitcnt vmcnt(0)" ::: "memory");
    }
    __builtin_amdgcn_s_barrier();

    // read ALL fragments of tile t into registers
    short8 bf[4][2];
#pragma unroll
    for (int g = 0; g < 4; ++g) {
      bf[g][0] = LD8(Bb, brow + g * 1024 + c0k);
      bf[g][1] = LD8(Bb, brow + g * 1024 + c1k);
    }
    short8 af[8][2];
#pragma unroll
    for (int mi = 0; mi < 8; ++mi) {
      af[mi][0] = LD8(Ab, arow + mi * 1024 + c0k);
      af[mi][1] = LD8(Ab, arow + mi * 1024 + c1k);
    }
    asm volatile("s_waitcnt lgkmcnt(0)" ::: "memory");
    __builtin_amdgcn_s_barrier();   // all waves done with buf[cur] -> free it

    // refill the freed buffer with tile t+2 (overlaps MFMA cluster below)
    if (t < 30) {
      stageA(cur, t + 2);
      stageB(cur, t + 2);
    }

    __builtin_amdgcn_s_setprio(1);
#pragma unroll
    for (int mi = 0; mi < 8; ++mi)
#pragma unroll
      for (int g = 0; g < 4; ++g) {
        acc[mi][g] = __builtin_amdgcn_mfma_f32_16x16x32_bf16(
            af[mi][0], bf[g][0], acc[mi][g], 0, 0, 0);
        acc[mi][g] = __builtin_amdgcn_mfma_f32_16x16x32_bf16(
            af[mi][1], bf[g][1], acc[mi][g], 0, 0, 0);
      }
    __builtin_amdgcn_s_setprio(0);
  }

  // ---- fused epilogue: bias + gates + cell update ----
  const int col = n0 + wc * 16 + fl;
  float bv[4];
#pragma unroll
  for (int g = 0; g < 4; ++g) bv[g] = bias[g * 1024 + col];

#pragma unroll
  for (int mi = 0; mi < 8; ++mi) {
#pragma unroll
    for (int r = 0; r < 4; ++r) {
      const int row = m0 + wr * 128 + mi * 16 + hi * 4 + r;
      const float zi = acc[mi][0][r] + bv[0];
      const float zf = acc[mi][1][r] + bv[1];
      const float zg = acc[mi][2][r] + bv[2];
      const float zo = acc[mi][3][r] + bv[3];
      const float ig = 1.f / (1.f + __expf(-zi));
      const float fg = 1.f / (1.f + __expf(-zf));
      const float gg = 1.f - 2.f / (__expf(2.f * zg) + 1.f);  // tanh
      const float og = 1.f / (1.f + __expf(-zo));
      const float c0v = c0[(size_t)row * 1024 + col];
      const float c1 = fg * c0v + ig * gg;
      const float h1 = og * c1;
      out[(size_t)row * 1024 + col] = h1;
      out[(size_t)4194304 + (size_t)row * 1024 + col] = c1;
    }
  }
}

// ---------------------------------------------------------------------------
extern "C" void kernel_launch(void* const* d_in, const int* in_sizes, int n_in,
                              void* d_out, int out_size, void* d_ws, size_t ws_size,
                              hipStream_t stream) {
  const float* x  = (const float*)d_in[0];
  const float* h0 = (const float*)d_in[1];
  const float* c0 = (const float*)d_in[2];
  Ptrs8 w, b;
  for (int i = 0; i < 4; ++i) {
    w.p[i]     = (const float*)d_in[3 + 2 * i];
    b.p[i]     = (const float*)d_in[4 + 2 * i];
    w.p[4 + i] = (const float*)d_in[11 + 2 * i];
    b.p[4 + i] = (const float*)d_in[12 + 2 * i];
  }
  u16* Wt = (u16*)d_ws;                                        // 16 MB
  u16* Ap = (u16*)((char*)d_ws + (size_t)4096 * 2048 * 2);     // 16 MB
  float* bias = (float*)((char*)d_ws + (size_t)2 * 4096 * 2048 * 2);  // 16 KB
  float* out = (float*)d_out;

  wt_pack<<<2048, 256, 0, stream>>>(w, Wt);
  xh_pack<<<4096, 256, 0, stream>>>(x, h0, Ap);
  bias_pack<<<4, 1024, 0, stream>>>(b, bias);
  lstm_fused<<<256, 512, 0, stream>>>(Ap, c0, Wt, bias, out);
}

// Round 9
// 91.952 us; speedup vs baseline: 1.1998x; 1.0182x over previous
//
#include <hip/hip_runtime.h>

typedef unsigned short u16;
typedef unsigned int u32;
typedef __attribute__((ext_vector_type(8))) short short8;
typedef __attribute__((ext_vector_type(4))) float f32x4;

__device__ __forceinline__ u16 f2b(float f) {
  u32 u = __builtin_bit_cast(u32, f);
  u32 r = (u + 0x7FFFu + ((u >> 16) & 1u)) >> 16;  // RNE f32->bf16
  return (u16)r;
}

__device__ __forceinline__ void gl_lds16(const void* g, void* l) {
  __builtin_amdgcn_global_load_lds(
      (const __attribute__((address_space(1))) u32*)g,
      (__attribute__((address_space(3))) u32*)l, 16, 0, 0);
}

struct Ptrs8 { const float* p[8]; };

// ---------------------------------------------------------------------------
// Pack/transpose+convert: Wt[g*1024 + n][h*1024 + k] = bf16(W[h*4+g][k][n])
// ---------------------------------------------------------------------------
__global__ __launch_bounds__(256) void wt_pack(Ptrs8 w, u16* __restrict__ Wt) {
  __shared__ float lds[64 * 64];     // 16 KB
  const int tid = threadIdx.x;
  const int bid = blockIdx.x;
  const int mat = bid >> 8;            // 0..7
  const int g = mat & 3, h = mat >> 2;
  const int tile = bid & 255;
  const int kt = tile >> 4, nt = tile & 15;
  const float* __restrict__ src = w.p[mat];

#pragma unroll
  for (int i = 0; i < 4; ++i) {
    int c = tid + i * 256;
    int k = c >> 4, n4 = (c & 15) * 4;
    gl_lds16(src + (size_t)(kt * 64 + k) * 1024 + nt * 64 + n4, &lds[c * 4]);
  }
  asm volatile("s_waitcnt vmcnt(0)");
  __syncthreads();

#pragma unroll
  for (int i = 0; i < 2; ++i) {
    int c = tid + i * 256;
    int n = c & 63, kb = (c >> 6) * 8;
    short8 v;
#pragma unroll
    for (int j = 0; j < 8; ++j) v[j] = (short)f2b(lds[(kb + j) * 64 + n]);
    size_t off = (size_t)(g * 1024 + nt * 64 + n) * 2048 + h * 1024 + kt * 64 + kb;
    *reinterpret_cast<short8*>(Wt + off) = v;
  }
}

// Ap[m][k] (bf16, [4096][2048]) = bf16( k<1024 ? x[m][k] : h0[m][k-1024] )
__global__ __launch_bounds__(256) void xh_pack(const float* __restrict__ x,
                                               const float* __restrict__ h0,
                                               u16* __restrict__ Ap) {
  int t = blockIdx.x * 256 + threadIdx.x;
  int m = t >> 8, kc = t & 255;
  const float* src = (kc < 128) ? (x + (size_t)m * 1024 + kc * 8)
                                : (h0 + (size_t)m * 1024 + (kc - 128) * 8);
  float4 a = *reinterpret_cast<const float4*>(src);
  float4 b = *reinterpret_cast<const float4*>(src + 4);
  short8 v;
  v[0] = (short)f2b(a.x); v[1] = (short)f2b(a.y);
  v[2] = (short)f2b(a.z); v[3] = (short)f2b(a.w);
  v[4] = (short)f2b(b.x); v[5] = (short)f2b(b.y);
  v[6] = (short)f2b(b.z); v[7] = (short)f2b(b.w);
  *reinterpret_cast<short8*>(Ap + (size_t)m * 2048 + kc * 8) = v;
}

__global__ void bias_pack(Ptrs8 b, float* __restrict__ bias) {
  int i = blockIdx.x * 1024 + threadIdx.x;
  int g = i >> 10, n = i & 1023;
  bias[i] = b.p[g][n] + b.p[4 + g][n];
}

// ---------------------------------------------------------------------------
// Fused LSTM GEMM — 4-phase fine interleave, race-free half-tile pipeline:
// 512 thr / 8 waves (2M x 4N), block 256m x (64n x 4 gates), BK=64, 32 iters.
// Per phase: vmcnt(4) -> barrier -> quadrant ds_reads -> half-tile stage issue
// -> prio1 -> 16 MFMA -> prio0.  ONE barrier per phase.  Stage order
// Bh0,Ah0,Ah1,Bh1 gives each half-tile 3 phases of flight; steady-state waits
// are all vmcnt(4) (tile-t half retires, tile-t+1 halves stay in flight).
// Wait->barrier->read ordering fixes r8's cross-wave DMA visibility race.
// ---------------------------------------------------------------------------
#define LD8(base, off) (*reinterpret_cast<const short8*>((base) + (off)))
#define MFMA_(a, b, c) __builtin_amdgcn_mfma_f32_16x16x32_bf16(a, b, c, 0, 0, 0)

#define READ_A(DST, BASE)                                   \
  _Pragma("unroll")                                         \
  for (int mi = 0; mi < 4; ++mi) {                          \
    DST[mi][0] = LD8(Ab, arow + (BASE + mi) * 1024 + c0k);  \
    DST[mi][1] = LD8(Ab, arow + (BASE + mi) * 1024 + c1k);  \
  }
#define READ_B(DST, GB)                                     \
  _Pragma("unroll")                                         \
  for (int g = 0; g < 2; ++g) {                             \
    DST[g][0] = LD8(Bb, bbase + (GB + g) * 4096 + c0k);     \
    DST[g][1] = LD8(Bb, bbase + (GB + g) * 4096 + c1k);     \
  }
#define MFMA_QUAD(AF, BF, MO, GO)                                              \
  __builtin_amdgcn_s_setprio(1);                                               \
  _Pragma("unroll")                                                            \
  for (int mi = 0; mi < 4; ++mi)                                               \
    _Pragma("unroll")                                                          \
    for (int g = 0; g < 2; ++g) {                                              \
      acc[MO + mi][GO + g] = MFMA_(AF[mi][0], BF[g][0], acc[MO + mi][GO + g]); \
      acc[MO + mi][GO + g] = MFMA_(AF[mi][1], BF[g][1], acc[MO + mi][GO + g]); \
    }                                                                          \
  __builtin_amdgcn_s_setprio(0);

__global__ __launch_bounds__(512, 2) void lstm_fused(
    const u16* __restrict__ Ap, const float* __restrict__ c0,
    const u16* __restrict__ Wt, const float* __restrict__ bias,
    float* __restrict__ out) {
  __shared__ u16 As[2][256 * 64];   // 32 KB each
  __shared__ u16 Bs[2][256 * 64];   // 32 KB each

  const int tid = threadIdx.x;
  const int lane = tid & 63;
  const int wid = tid >> 6;
  const int wr = wid >> 2;          // M half
  const int wc = wid & 3;           // n-16 block
  const int fl = lane & 15;
  const int hi = lane >> 4;
  const int lo7 = fl & 7;

  const int bid0 = blockIdx.x;
  const int sbid = (bid0 & 7) * 32 + (bid0 >> 3);  // XCD swizzle (256%8==0)
  const int m0 = (sbid >> 4) * 256;
  const int n0 = (sbid & 15) * 64;

  // ---- stage maps: 2048 16B-chunks per tile, 4/thread, linear LDS dest,
  //      global source pre-swizzled: chunk cg = cL ^ (row & 7).
  // A chunk i: rows [i*64,(i+1)*64); half0={0,2}, half1={1,3}.
  // B LDS row = g*64 + wc*16 + u; chunk i = gate i; half0={0,1}, half1={2,3}.
  int aoff[4], boff[4];
#pragma unroll
  for (int i = 0; i < 4; ++i) {
    const int L = tid + i * 512;
    const int r = L >> 3, cL = L & 7;
    const int cg = cL ^ (r & 7);
    aoff[i] = (m0 + r) * 2048 + cg * 8;
    const int ge = r >> 6, wce = (r >> 4) & 3, ue = r & 15;
    boff[i] = (ge * 1024 + n0 + wce * 16 + ue) * 2048 + cg * 8;
  }

  auto stageA = [&](int buf, int t, int h) {  // half h: chunks {h, h+2}
    const int k0 = t * 64;
    gl_lds16(Ap + aoff[h] + k0, &As[buf][(tid + h * 512) * 8]);
    gl_lds16(Ap + aoff[h + 2] + k0, &As[buf][(tid + (h + 2) * 512) * 8]);
  };
  auto stageB = [&](int buf, int t, int h) {  // half h: chunks {2h, 2h+1}
    const int k0 = t * 64;
    gl_lds16(Wt + boff[2 * h] + k0, &Bs[buf][(tid + (2 * h) * 512) * 8]);
    gl_lds16(Wt + boff[2 * h + 1] + k0, &Bs[buf][(tid + (2 * h + 1) * 512) * 8]);
  };

  // ---- fragment read bases (element offsets; lane-constant swizzle) ----
  const int c0k = (hi ^ lo7) * 8;          // ks=0 swizzled chunk
  const int c1k = ((4 + hi) ^ lo7) * 8;    // ks=1
  const int arow = (wr * 128 + fl) * 64;
  const int bbase = (wc * 16 + fl) * 64;   // + g*4096

  f32x4 acc[8][4] = {};   // [mi][gate]

  // prologue: tile 0 in steady-state issue order Bh0, Ah0, Ah1, Bh1
  stageB(0, 0, 0);
  stageA(0, 0, 0);
  stageA(0, 0, 1);
  stageB(0, 0, 1);

  for (int t = 0; t < 31; ++t) {
    const int cur = t & 1, nxt = cur ^ 1;
    const u16* Ab = &As[cur][0];
    const u16* Bb = &Bs[cur][0];
    short8 af03[4][2], af47[4][2], bf01[2][2], bf23[2][2];

    // P1: wait Bh0(t)+Ah0(t); read af03,bf01; stage Bh0(t+1)
    asm volatile("s_waitcnt vmcnt(4)" ::: "memory");
    __builtin_amdgcn_s_barrier();
    READ_A(af03, 0)
    READ_B(bf01, 0)
    stageB(nxt, t + 1, 0);
    MFMA_QUAD(af03, bf01, 0, 0)

    // P2: wait Ah1(t); read af47; stage Ah0(t+1)
    asm volatile("s_waitcnt vmcnt(4)" ::: "memory");
    __builtin_amdgcn_s_barrier();
    READ_A(af47, 4)
    stageA(nxt, t + 1, 0);
    MFMA_QUAD(af47, bf01, 4, 0)

    // P3: wait Bh1(t); read bf23; stage Ah1(t+1)
    asm volatile("s_waitcnt vmcnt(4)" ::: "memory");
    __builtin_amdgcn_s_barrier();
    READ_B(bf23, 2)
    stageA(nxt, t + 1, 1);
    MFMA_QUAD(af03, bf23, 0, 2)

    // P4: no wait; stage Bh1(t+1)
    __builtin_amdgcn_s_barrier();
    stageB(nxt, t + 1, 1);
    MFMA_QUAD(af47, bf23, 4, 2)
  }

  // ---- t = 31 peeled (no stages; drain waits 4 -> 2 -> 0) ----
  {
    const u16* Ab = &As[1][0];
    const u16* Bb = &Bs[1][0];
    short8 af03[4][2], af47[4][2], bf01[2][2], bf23[2][2];

    asm volatile("s_waitcnt vmcnt(4)" ::: "memory");
    __builtin_amdgcn_s_barrier();
    READ_A(af03, 0)
    READ_B(bf01, 0)
    MFMA_QUAD(af03, bf01, 0, 0)

    asm volatile("s_waitcnt vmcnt(2)" ::: "memory");
    __builtin_amdgcn_s_barrier();
    READ_A(af47, 4)
    MFMA_QUAD(af47, bf01, 4, 0)

    asm volatile("s_waitcnt vmcnt(0)" ::: "memory");
    __builtin_amdgcn_s_barrier();
    READ_B(bf23, 2)
    MFMA_QUAD(af03, bf23, 0, 2)

    __builtin_amdgcn_s_barrier();
    MFMA_QUAD(af47, bf23, 4, 2)
  }

  // ---- fused epilogue: bias + gates + cell update ----
  const int col = n0 + wc * 16 + fl;
  float bv[4];
#pragma unroll
  for (int g = 0; g < 4; ++g) bv[g] = bias[g * 1024 + col];

#pragma unroll
  for (int mi = 0; mi < 8; ++mi) {
#pragma unroll
    for (int r = 0; r < 4; ++r) {
      const int row = m0 + wr * 128 + mi * 16 + hi * 4 + r;
      const float zi = acc[mi][0][r] + bv[0];
      const float zf = acc[mi][1][r] + bv[1];
      const float zg = acc[mi][2][r] + bv[2];
      const float zo = acc[mi][3][r] + bv[3];
      const float ig = 1.f / (1.f + __expf(-zi));
      const float fg = 1.f / (1.f + __expf(-zf));
      const float gg = 1.f - 2.f / (__expf(2.f * zg) + 1.f);  // tanh
      const float og = 1.f / (1.f + __expf(-zo));
      const float c0v = c0[(size_t)row * 1024 + col];
      const float c1 = fg * c0v + ig * gg;
      const float h1 = og * c1;
      out[(size_t)row * 1024 + col] = h1;
      out[(size_t)4194304 + (size_t)row * 1024 + col] = c1;
    }
  }
}

// ---------------------------------------------------------------------------
extern "C" void kernel_launch(void* const* d_in, const int* in_sizes, int n_in,
                              void* d_out, int out_size, void* d_ws, size_t ws_size,
                              hipStream_t stream) {
  const float* x  = (const float*)d_in[0];
  const float* h0 = (const float*)d_in[1];
  const float* c0 = (const float*)d_in[2];
  Ptrs8 w, b;
  for (int i = 0; i < 4; ++i) {
    w.p[i]     = (const float*)d_in[3 + 2 * i];
    b.p[i]     = (const float*)d_in[4 + 2 * i];
    w.p[4 + i] = (const float*)d_in[11 + 2 * i];
    b.p[4 + i] = (const float*)d_in[12 + 2 * i];
  }
  u16* Wt = (u16*)d_ws;                                        // 16 MB
  u16* Ap = (u16*)((char*)d_ws + (size_t)4096 * 2048 * 2);     // 16 MB
  float* bias = (float*)((char*)d_ws + (size_t)2 * 4096 * 2048 * 2);  // 16 KB
  float* out = (float*)d_out;

  wt_pack<<<2048, 256, 0, stream>>>(w, Wt);
  xh_pack<<<4096, 256, 0, stream>>>(x, h0, Ap);
  bias_pack<<<4, 1024, 0, stream>>>(b, bias);
  lstm_fused<<<256, 512, 0, stream>>>(Ap, c0, Wt, bias, out);
}